// Round 19
// baseline (119.904 us; speedup 1.0000x reference)
//
#include <hip/hip_runtime.h>
#include <hip/hip_bf16.h>

#define TB 256

typedef __attribute__((ext_vector_type(8))) short short8;
typedef __attribute__((ext_vector_type(4))) unsigned int uint4v;
typedef __attribute__((ext_vector_type(4))) float f32x4;

// Problem constants: B=16, C=64, L=16384, HOP=256, KS=3, DIL=3, KL=64
// ws: ktf u32[16 b][96 chunk][64 f][128 slot] = 50,331,648 B  (chunk=(kk*4+jp)*4+hi)
//     wf  u32[6144]                            = 24,576 B
#define KTF_BYTES 50331648ull
#define WS_NEED   (KTF_BYTES + 24576ull)

static __device__ __forceinline__ float lrelu(float v){ return v > 0.f ? v : 0.2f*v; }

static __device__ __forceinline__ unsigned int pack2(float lo, float hi){
    __hip_bfloat162 h = __float22bfloat162_rn(float2{lo, hi});
    unsigned int r;
    __builtin_memcpy(&r, &h, 4);
    return r;
}

static __device__ __forceinline__ float bf2f(unsigned int u16v){
    return __uint_as_float(u16v << 16);
}

// sigmoid(a)*tanh(t) = (v-1) / ((1+u)(v+1)),  u=e^-a, v=e^{2t}
static __device__ __forceinline__ float glu_gate(float a, float t){
    float u = __expf(-a);
    float v = __expf(2.0f * t);
    float den = (1.0f + u) * (v + 1.0f);
    return (v - 1.0f) * __builtin_amdgcn_rcpf(den);
}

// ---------------------------------------------------------------------------
// A-frag pair: u32 = bf16{A[ch][r], A[ch][r+1]}, r = kk*32 + hi*8 + 2jp
// slot s = mt*16 + row; GLU same-lane map (mt 0..7):
//   row&2==0 -> sigmoid ch = mt*8 + 2*(row>>2) + (row&1)
//   row&2==2 -> tanh    ch = 64 + mt*8 + 2*(row>>2) + (row&1)
// ktf addr: ((b*96 + (kk*4+jp)*4 + hi)*64 + f)*128 + slot

__global__ __launch_bounds__(256, 4)
void ktf_transpose(const float* __restrict__ kern, unsigned int* __restrict__ ktf)
{
    __shared__ unsigned int tl32[128 * 65];            // [oc][f pad65], 33280 B
    const int tid = threadIdx.x;
    const int blk = blockIdx.x;                        // 1536 = b*96 + ci2*3 + k
    const int k   = blk % 3;
    const int ci2 = (blk / 3) % 32;
    const int b   = blk / 96;
    const int kk  = k*2 + (ci2 >> 4);
    const int hi  = (ci2 >> 2) & 3;
    const int jp  = ci2 & 3;

    const float* src0 = kern + (size_t)b*1572864 + (size_t)ci2*49152 + k*64;
    #pragma unroll
    for (int it = 0; it < 8; ++it) {
        int p = tid + it*TB;                           // 2048 = 128 oc * 16 fq
        int oc = p >> 4, fq = p & 15;
        const float* s = src0 + oc*192 + fq*4;
        float4 v0 = *(const float4*)(s);               // ci even
        float4 v1 = *(const float4*)(s + 24576);       // ci odd
        unsigned int* d = tl32 + oc*65 + fq*4;
        d[0] = pack2(v0.x, v1.x);
        d[1] = pack2(v0.y, v1.y);
        d[2] = pack2(v0.z, v1.z);
        d[3] = pack2(v0.w, v1.w);
    }
    __syncthreads();

    const int l = tid & 63, wvv = tid >> 6;
    const int c = (kk*4 + jp)*4 + hi;
    const int oc0 = 2*l;                               // even channel
    const int slot0 = (oc0 < 64)
        ? ((oc0 >> 3)*16 + ((oc0 & 7) >> 1)*4)
        : (((oc0 - 64) >> 3)*16 + (((oc0 - 64) & 7) >> 1)*4 + 2);
    unsigned int* dst = ktf + (size_t)(b*96 + c)*8192 + slot0;
    const int f0 = wvv*16;
    #pragma unroll
    for (int fi = 0; fi < 16; ++fi) {
        int f = f0 + fi;
        uint2 v;
        v.x = tl32[(oc0    )*65 + f];
        v.y = tl32[(oc0 + 1)*65 + f];
        *(uint2*)(dst + f*128) = v;
    }
}

// conv_w[co][ci][k] -> wf (conv A-frags, plain m = mt*16+lo mapping)
__global__ __launch_bounds__(256, 4)
void wf_prep(const float* __restrict__ conv_w, unsigned int* __restrict__ wf)
{
    int u = blockIdx.x*TB + threadIdx.x;               // 6144
    int ln = u & 63, mt = (u >> 6) & 3, jp = (u >> 8) & 3, kk = u >> 10;
    int lo = ln & 15, hi = ln >> 4;
    int m  = mt*16 + lo;
    int k  = kk >> 1, ci = (kk & 1)*32 + hi*8 + jp*2;
    float a0 = conv_w[m*192 + ci*3 + k];
    float a1 = conv_w[m*192 + (ci + 1)*3 + k];
    wf[u] = pack2(a0, a1);
}

// ---------------------------------------------------------------------------
// LDS: xt[144][64ci] bf16 swz @0 (18432B)  [single buffer, reused per half]
//      ht[144][64]   bf16 swz @18432 (18432B)
//      bias_lds[128] f32 @36864 (512B)  -> 37376 B total
#define LDS_HT   18432
#define LDS_BIAS 36864

// load one half-tile of x into registers (issued; not yet waited)
#define X_LOAD(TS_, XV_)                                                      \
    do {                                                                      \
        const int ts_ = (TS_);                                                \
        const bool inter_ = (ts_ >= 0) & (ts_ + 143 < 16384);                 \
        if (inter_) {                                                         \
            _Pragma("unroll")                                                 \
            for (int it = 0; it < 2; ++it)                                    \
                if (it == 0 || ln < 8) {                                      \
                    int t = ts_ + 2*ln + it*128;                              \
                    _Pragma("unroll")                                         \
                    for (int j = 0; j < 8; ++j)                               \
                        XV_[it][j] = *(const float2*)(xb + j*16384 + t);      \
                }                                                             \
        } else {                                                              \
            _Pragma("unroll")                                                 \
            for (int it = 0; it < 2; ++it)                                    \
                if (it == 0 || ln < 8) {                                      \
                    int t = ts_ + 2*ln + it*128;                              \
                    _Pragma("unroll")                                         \
                    for (int j = 0; j < 8; ++j) {                             \
                        float a0_ = ((unsigned)t       < 16384u) ? xb[j*16384 + t    ] : 0.f; \
                        float a1_ = ((unsigned)(t + 1) < 16384u) ? xb[j*16384 + t + 1] : 0.f; \
                        XV_[it][j] = make_float2(a0_, a1_);                   \
                    }                                                         \
                }                                                             \
        }                                                                     \
    } while (0)

// pack + store registers -> xt buffer (base 0)
#define X_STORE(XV_)                                                          \
    do {                                                                      \
        _Pragma("unroll")                                                     \
        for (int it = 0; it < 2; ++it)                                        \
            if (it == 0 || ln < 8) {                                          \
                int p0 = 2*ln + it*128;                                       \
                unsigned int w0_[4], w1_[4];                                  \
                _Pragma("unroll")                                             \
                for (int jq = 0; jq < 4; ++jq) {                              \
                    float2 e0_ = XV_[it][2*jq], e1_ = XV_[it][2*jq + 1];      \
                    w0_[jq] = pack2(lrelu(e0_.x), lrelu(e1_.x));              \
                    w1_[jq] = pack2(lrelu(e0_.y), lrelu(e1_.y));              \
                }                                                             \
                int a0_ = ( p0     *128 + wv*16) ^ (( p0      & 7) << 4);     \
                int a1_ = ((p0 + 1)*128 + wv*16) ^ (((p0 + 1) & 7) << 4);     \
                *(uint4*)(lds + a0_) = make_uint4(w0_[0], w0_[1], w0_[2], w0_[3]); \
                *(uint4*)(lds + a1_) = make_uint4(w1_[0], w1_[1], w1_[2], w1_[3]); \
            }                                                                 \
    } while (0)

// dilated conv: xt -> ht (aw reloaded from L2 each call; keeps VGPR peak low)
#define B_PHASE(TB_)                                                          \
    do {                                                                      \
        uint4v aw_[6];                                                        \
        _Pragma("unroll")                                                     \
        for (int kk = 0; kk < 6; ++kk) {                                      \
            int w0_ = kk*1024 + mt*64 + ln;                                   \
            aw_[kk].x = wf[w0_      ]; aw_[kk].y = wf[w0_ + 256];             \
            aw_[kk].z = wf[w0_ + 512]; aw_[kk].w = wf[w0_ + 768];             \
        }                                                                     \
        float4 cb4_ = *(const float4*)(conv_b + mt*16 + hi*4);                \
        const int n0_  = nth ? 5 : 0;                                         \
        const int cnt_ = nth ? 4 : 5;                                         \
        int bqa_[6];                                                          \
        _Pragma("unroll")                                                     \
        for (int kk = 0; kk < 6; ++kk) {                                      \
            int row_ = n0_*16 + lo + 3*(kk >> 1) + 1;                         \
            int cib_ = (kk & 1)*32 + hi*8;                                    \
            bqa_[kk] = (row_*128 + cib_*2) ^ ((row_ & 7) << 4);               \
        }                                                                     \
        int hta_ = LDS_HT + (((n0_*16 + lo)*128 + (mt*16 + hi*4)*2) ^ ((lo & 7) << 4)); \
        int pos_ = (TB_) + n0_*16 + lo - 8;                                   \
        _Pragma("unroll 1")                                                   \
        for (int i = 0; i < cnt_; ++i) {                                      \
            f32x4 acc_ = {0.f, 0.f, 0.f, 0.f};                                \
            __builtin_amdgcn_s_setprio(1);                                    \
            _Pragma("unroll")                                                 \
            for (int kk = 0; kk < 6; ++kk) {                                  \
                short8 bq_ = *(const short8*)(lds + bqa_[kk]);                \
                acc_ = __builtin_amdgcn_mfma_f32_16x16x32_bf16(               \
                        __builtin_bit_cast(short8, aw_[kk]), bq_, acc_, 0, 0, 0); \
            }                                                                 \
            __builtin_amdgcn_s_setprio(0);                                    \
            bool valid_ = (unsigned)pos_ < 16384u;                            \
            unsigned int h01_ = valid_ ? pack2(lrelu(acc_[0] + cb4_.x), lrelu(acc_[1] + cb4_.y)) : 0u; \
            unsigned int h23_ = valid_ ? pack2(lrelu(acc_[2] + cb4_.z), lrelu(acc_[3] + cb4_.w)) : 0u; \
            unsigned int* d_ = (unsigned int*)(lds + hta_);                   \
            d_[0] = h01_; d_[1] = h23_;                                       \
            _Pragma("unroll")                                                 \
            for (int kk = 0; kk < 6; ++kk) bqa_[kk] += 2048;                  \
            hta_ += 2048; pos_ += 16;                                         \
        }                                                                     \
    } while (0)

// LVC: ht (+ xt residual) -> out at time base TB_
#define C_PHASE(TB_)                                                          \
    do {                                                                      \
        int bqa_[6];                                                          \
        _Pragma("unroll")                                                     \
        for (int kk = 0; kk < 6; ++kk) {                                      \
            int row_ = lo + 7 + (kk >> 1);                                    \
            int cib_ = (kk & 1)*32 + hi*8;                                    \
            bqa_[kk] = LDS_HT + ((row_*128 + cib_*2) ^ ((row_ & 7) << 4));    \
        }                                                                     \
        const int q_  = lo + 12;                                              \
        int ra_ = (q_*128 + ch2*2) ^ ((q_ & 7) << 4);                         \
        float* ob_ = out + ((size_t)b*64 + ch2)*16384 + (TB_) + lo;           \
        _Pragma("unroll 1")                                                   \
        for (int i = 0; i < 8; ++i) {                                         \
            f32x4 acc_ = {0.f, 0.f, 0.f, 0.f};                                \
            __builtin_amdgcn_s_setprio(1);                                    \
            _Pragma("unroll")                                                 \
            for (int kk = 0; kk < 6; ++kk) {                                  \
                short8 bq_ = *(const short8*)(lds + bqa_[kk]);                \
                acc_ = __builtin_amdgcn_mfma_f32_16x16x32_bf16(               \
                        __builtin_bit_cast(short8, am[kk]), bq_, acc_, 0, 0, 0); \
            }                                                                 \
            __builtin_amdgcn_s_setprio(0);                                    \
            unsigned int rvc_ = *(const unsigned int*)(lds + ra_);            \
            float h0_ = bf2f(rvc_ & 0xFFFFu), h1_ = bf2f(rvc_ >> 16);         \
            float g0_ = glu_gate(acc_[0] + bs0, acc_[2] + bt0);               \
            float g1_ = glu_gate(acc_[1] + bs1, acc_[3] + bt1);               \
            ob_[(size_t)i*16]         = fminf(h0_, 5.0f*h0_) + g0_;           \
            ob_[16384 + (size_t)i*16] = fminf(h1_, 5.0f*h1_) + g1_;           \
            _Pragma("unroll")                                                 \
            for (int kk = 0; kk < 6; ++kk) bqa_[kk] += 2048;                  \
            ra_ += 2048;                                                      \
        }                                                                     \
    } while (0)

__global__ __launch_bounds__(512, 5)
void fused_kernel(const float* __restrict__ x,
                  const float* __restrict__ bias,
                  const float* __restrict__ conv_b,
                  const unsigned int* __restrict__ ktf,
                  const unsigned int* __restrict__ wf,
                  float* __restrict__ out)
{
    __shared__ char lds[37376];
    float* bias_lds = (float*)(lds + LDS_BIAS);

    const int tid = threadIdx.x;
    const int blk = blockIdx.x;                        // 1024 = b*64 + f
    const int b = blk >> 6, f = blk & 63;
    const int t0 = f << 8;
    const int ln = tid & 63, wv = tid >> 6;            // 8 waves
    const int lo = ln & 15, hi = ln >> 4;
    const int mt = wv & 3, nth = wv >> 2;

    const float* xb = x + ((size_t)b*64 + wv*8) * 16384;

    // ---- half 0: A (x loads first, am under their shadow) ----
    {
        float2 xv[2][8];
        X_LOAD(t0 - 12, xv);
        __builtin_amdgcn_sched_barrier(0);
        if (tid < 128) bias_lds[tid] = bias[(size_t)b*8192 + tid*64 + f];
        __builtin_amdgcn_sched_barrier(0);
        X_STORE(xv);
    }
    // am: once per block, reused by both halves
    uint4v am[6];
    {
        const unsigned int* kp = ktf + (size_t)b*786432 + hi*8192 + f*128 + wv*16 + lo;
        #pragma unroll
        for (int kk = 0; kk < 6; ++kk) {
            int o = kk*131072;                         // jp stride 32768
            am[kk].x = kp[o        ]; am[kk].y = kp[o + 32768];
            am[kk].z = kp[o + 65536]; am[kk].w = kp[o + 98304];
        }
    }
    __syncthreads();

    const int ch2 = wv*8 + 2*hi;
    const float bs0 = bias_lds[ch2],      bs1 = bias_lds[ch2 + 1];
    const float bt0 = bias_lds[ch2 + 64], bt1 = bias_lds[ch2 + 65];

    B_PHASE(t0);
    __syncthreads();
    C_PHASE(t0);
    __syncthreads();                                   // xt/ht reads done

    // ---- half 1: reload xt (short register liveness; no spill) ----
    {
        float2 xv[2][8];
        X_LOAD(t0 + 116, xv);                          // ts = t0 + 128 - 12
        X_STORE(xv);
    }
    __syncthreads();

    B_PHASE(t0 + 128);
    __syncthreads();
    C_PHASE(t0 + 128);
}

extern "C" void kernel_launch(void* const* d_in, const int* in_sizes, int n_in,
                              void* d_out, int out_size, void* d_ws, size_t ws_size,
                              hipStream_t stream)
{
    const float* x      = (const float*)d_in[0];
    const float* kern   = (const float*)d_in[1];
    const float* bias   = (const float*)d_in[2];
    const float* conv_b = (const float*)d_in[4];
    float* out = (float*)d_out;

    if (ws_size < WS_NEED) return;   // harness provides >=100MB (verified R0)

    unsigned int* ktf = (unsigned int*)d_ws;
    unsigned int* wf  = (unsigned int*)((char*)d_ws + KTF_BYTES);

    wf_prep      <<<dim3(24),   dim3(TB), 0, stream>>>((const float*)d_in[3], wf);
    ktf_transpose<<<dim3(1536), dim3(TB), 0, stream>>>(kern, ktf);
    fused_kernel <<<dim3(1024), dim3(512), 0, stream>>>(x, bias, conv_b, ktf, wf, out);
    (void)in_sizes; (void)n_in; (void)out_size;
}

// Round 20
// 83.718 us; speedup vs baseline: 1.4322x; 1.4322x over previous
//
#include <hip/hip_runtime.h>
#include <hip/hip_bf16.h>

#define TB 256

typedef __attribute__((ext_vector_type(8))) short short8;
typedef __attribute__((ext_vector_type(4))) unsigned int uint4v;
typedef __attribute__((ext_vector_type(4))) float f32x4;

// Problem constants: B=16, C=64, L=16384, HOP=256, KS=3, DIL=3, KL=64
// ws: ktf u32[16 b][96 chunk][64 f][128 slot] = 50,331,648 B  (chunk=(kk*4+jp)*4+hi)
//     wf  u32[6144]                            = 24,576 B
#define KTF_BYTES 50331648ull
#define WS_NEED   (KTF_BYTES + 24576ull)

static __device__ __forceinline__ float lrelu(float v){ return v > 0.f ? v : 0.2f*v; }

static __device__ __forceinline__ unsigned int pack2(float lo, float hi){
    __hip_bfloat162 h = __float22bfloat162_rn(float2{lo, hi});
    unsigned int r;
    __builtin_memcpy(&r, &h, 4);
    return r;
}

static __device__ __forceinline__ float bf2f(unsigned int u16v){
    return __uint_as_float(u16v << 16);
}

// sigmoid(a)*tanh(t) = (v-1) / ((1+u)(v+1)),  u=e^-a, v=e^{2t}
// no clamp: |t| is small here; e^{2t} overflows only at t>44 (impossible)
static __device__ __forceinline__ float glu_gate(float a, float t){
    float u = __expf(-a);
    float v = __expf(2.0f * t);
    float den = (1.0f + u) * (v + 1.0f);
    return (v - 1.0f) * __builtin_amdgcn_rcpf(den);
}

// ---------------------------------------------------------------------------
// A-frag pair: u32 = bf16{A[ch][r], A[ch][r+1]}, r = kk*32 + hi*8 + 2jp
// slot s = mt*16 + row; GLU same-lane map (mt 0..7):
//   row&2==0 -> sigmoid ch = mt*8 + 2*(row>>2) + (row&1)
//   row&2==2 -> tanh    ch = 64 + mt*8 + 2*(row>>2) + (row&1)
// ktf addr: ((b*96 + (kk*4+jp)*4 + hi)*64 + f)*128 + slot

__global__ __launch_bounds__(256, 4)
void ktf_transpose(const float* __restrict__ kern, unsigned int* __restrict__ ktf)
{
    __shared__ unsigned int tl32[128 * 65];            // [oc][f pad65], 33280 B
    const int tid = threadIdx.x;
    const int blk = blockIdx.x;                        // 1536 = b*96 + ci2*3 + k
    const int k   = blk % 3;
    const int ci2 = (blk / 3) % 32;
    const int b   = blk / 96;
    const int kk  = k*2 + (ci2 >> 4);
    const int hi  = (ci2 >> 2) & 3;
    const int jp  = ci2 & 3;

    const float* src0 = kern + (size_t)b*1572864 + (size_t)ci2*49152 + k*64;
    #pragma unroll
    for (int it = 0; it < 8; ++it) {
        int p = tid + it*TB;                           // 2048 = 128 oc * 16 fq
        int oc = p >> 4, fq = p & 15;
        const float* s = src0 + oc*192 + fq*4;
        float4 v0 = *(const float4*)(s);               // ci even
        float4 v1 = *(const float4*)(s + 24576);       // ci odd
        unsigned int* d = tl32 + oc*65 + fq*4;
        d[0] = pack2(v0.x, v1.x);
        d[1] = pack2(v0.y, v1.y);
        d[2] = pack2(v0.z, v1.z);
        d[3] = pack2(v0.w, v1.w);
    }
    __syncthreads();

    const int l = tid & 63, wvv = tid >> 6;
    const int c = (kk*4 + jp)*4 + hi;
    const int oc0 = 2*l;                               // even channel
    const int slot0 = (oc0 < 64)
        ? ((oc0 >> 3)*16 + ((oc0 & 7) >> 1)*4)
        : (((oc0 - 64) >> 3)*16 + (((oc0 - 64) & 7) >> 1)*4 + 2);
    unsigned int* dst = ktf + (size_t)(b*96 + c)*8192 + slot0;
    const int f0 = wvv*16;
    #pragma unroll
    for (int fi = 0; fi < 16; ++fi) {
        int f = f0 + fi;
        uint2 v;
        v.x = tl32[(oc0    )*65 + f];
        v.y = tl32[(oc0 + 1)*65 + f];
        *(uint2*)(dst + f*128) = v;
    }
}

// conv_w[co][ci][k] -> wf (conv A-frags, plain m = mt*16+lo mapping)
__global__ __launch_bounds__(256, 4)
void wf_prep(const float* __restrict__ conv_w, unsigned int* __restrict__ wf)
{
    int u = blockIdx.x*TB + threadIdx.x;               // 6144
    int ln = u & 63, mt = (u >> 6) & 3, jp = (u >> 8) & 3, kk = u >> 10;
    int lo = ln & 15, hi = ln >> 4;
    int m  = mt*16 + lo;
    int k  = kk >> 1, ci = (kk & 1)*32 + hi*8 + jp*2;
    float a0 = conv_w[m*192 + ci*3 + k];
    float a1 = conv_w[m*192 + (ci + 1)*3 + k];
    wf[u] = pack2(a0, a1);
}

// ---------------------------------------------------------------------------
// LDS: xt[144][64ci] bf16 swizzled @0 (18432B)
//      ht[144][64]   bf16 swizzled @18432 (18432B)
//      bias_lds[128] f32 @36864 (512B)  -> 37376 B total
#define LDS_HT   18432
#define LDS_BIAS 36864

__global__ __launch_bounds__(512, 6)
void fused_kernel(const float* __restrict__ x,
                  const float* __restrict__ bias,
                  const float* __restrict__ conv_b,
                  const unsigned int* __restrict__ ktf,
                  const unsigned int* __restrict__ wf,
                  float* __restrict__ out)
{
    __shared__ char lds[37376];
    float* bias_lds = (float*)(lds + LDS_BIAS);

    const int tid = threadIdx.x;
    const int blk = blockIdx.x;                        // 2048 = (b*64+f)*2 + h
    const int h = blk & 1;
    const int bf = blk >> 1;
    const int b = bf >> 6, f = bf & 63;
    const int t0 = f << 8;
    const int tb = t0 + h*128;                         // this block's 128 positions
    const int ln = tid & 63, wv = tid >> 6;            // 8 waves
    const int lo = ln & 15, hi = ln >> 4;
    const int mt = wv & 3, nth = wv >> 2;

    if (tid < 128) bias_lds[tid] = bias[(size_t)b*8192 + tid*64 + f];

    // ---- A: load x half-tile (transposed, lrelu, bf16) -> xt[144][64] ----
    {
        const float* xb = x + ((size_t)b*64 + wv*8) * 16384;  // wave's ci octet
        const int ts = tb - 12;                        // xt row q <-> t = ts + q
        const bool interior = (ts >= 0) & (ts + 143 < 16384);
        #pragma unroll
        for (int it = 0; it < 3; ++it) {
            int p = (it < 2) ? (ln + it*64) : (128 + ln);
            if (it < 2 || ln < 16) {
                int t = ts + p;
                float v[8];
                if (interior) {
                    #pragma unroll
                    for (int j = 0; j < 8; ++j) v[j] = xb[j*16384 + t];
                } else {
                    bool ok = (unsigned)t < 16384u;
                    #pragma unroll
                    for (int j = 0; j < 8; ++j) v[j] = ok ? xb[j*16384 + t] : 0.f;
                }
                unsigned int w0 = pack2(lrelu(v[0]), lrelu(v[1]));
                unsigned int w1 = pack2(lrelu(v[2]), lrelu(v[3]));
                unsigned int w2 = pack2(lrelu(v[4]), lrelu(v[5]));
                unsigned int w3 = pack2(lrelu(v[6]), lrelu(v[7]));
                int a = (p*128 + wv*16) ^ ((p & 7) << 4);
                *(uint4*)(lds + a) = make_uint4(w0, w1, w2, w3);
            }
        }
    }
    __syncthreads();

    // ---- B: dilated conv via MFMA; wave (mt, nth); ht rows 0..143 ----
    {
        uint4v aw[6];
        #pragma unroll
        for (int kk = 0; kk < 6; ++kk) {
            int w0 = kk*1024 + mt*64 + ln;
            aw[kk].x = wf[w0      ]; aw[kk].y = wf[w0 + 256];
            aw[kk].z = wf[w0 + 512]; aw[kk].w = wf[w0 + 768];
        }
        float4 cb4 = *(const float4*)(conv_b + mt*16 + hi*4);
        const int n0  = nth ? 5 : 0;
        const int cnt = nth ? 4 : 5;                   // nt 0..4 | 5..8
        int bqa[6];
        #pragma unroll
        for (int kk = 0; kk < 6; ++kk) {
            int row = n0*16 + lo + 3*(kk >> 1) + 1;
            int cib = (kk & 1)*32 + hi*8;
            bqa[kk] = (row*128 + cib*2) ^ ((row & 7) << 4);
        }
        int hta = LDS_HT + (((n0*16 + lo)*128 + (mt*16 + hi*4)*2) ^ ((lo & 7) << 4));
        int pos = tb + n0*16 + lo - 8;
        #pragma unroll 1
        for (int i = 0; i < cnt; ++i) {
            f32x4 acc = {0.f, 0.f, 0.f, 0.f};
            __builtin_amdgcn_s_setprio(1);
            #pragma unroll
            for (int kk = 0; kk < 6; ++kk) {
                short8 bq = *(const short8*)(lds + bqa[kk]);
                acc = __builtin_amdgcn_mfma_f32_16x16x32_bf16(
                        __builtin_bit_cast(short8, aw[kk]), bq, acc, 0, 0, 0);
            }
            __builtin_amdgcn_s_setprio(0);

            bool valid = (unsigned)pos < 16384u;
            unsigned int h01 = valid ? pack2(lrelu(acc[0] + cb4.x), lrelu(acc[1] + cb4.y)) : 0u;
            unsigned int h23 = valid ? pack2(lrelu(acc[2] + cb4.z), lrelu(acc[3] + cb4.w)) : 0u;
            unsigned int* d = (unsigned int*)(lds + hta);
            d[0] = h01; d[1] = h23;

            #pragma unroll
            for (int kk = 0; kk < 6; ++kk) bqa[kk] += 2048;
            hta += 2048; pos += 16;
        }
    }
    __syncthreads();

    // ---- C: LVC via MFMA; wave wv owns GLU m-tile (c0=wv*8), same-lane pairs ----
    {
        uint4v am[6];
        const unsigned int* kp = ktf + (size_t)b*786432 + hi*8192 + f*128 + wv*16 + lo;
        #pragma unroll
        for (int kk = 0; kk < 6; ++kk) {
            int o = kk*131072;                         // jp stride 32768
            am[kk].x = kp[o        ]; am[kk].y = kp[o + 32768];
            am[kk].z = kp[o + 65536]; am[kk].w = kp[o + 98304];
        }
        const int c0 = wv*8;
        const int ch2 = c0 + 2*hi;                     // this lane's channel pair
        float bs0 = bias_lds[ch2],      bs1 = bias_lds[ch2 + 1];
        float bt0 = bias_lds[ch2 + 64], bt1 = bias_lds[ch2 + 65];

        int bqa[6];
        #pragma unroll
        for (int kk = 0; kk < 6; ++kk) {
            int row = lo + 7 + (kk >> 1);
            int cib = (kk & 1)*32 + hi*8;
            bqa[kk] = LDS_HT + ((row*128 + cib*2) ^ ((row & 7) << 4));
        }
        int q  = lo + 12;
        int ra = (q*128 + ch2*2) ^ ((q & 7) << 4);
        float* ob = out + ((size_t)b*64 + ch2)*16384 + tb + lo;

        #pragma unroll 1
        for (int i = 0; i < 8; ++i) {
            f32x4 acc = {0.f, 0.f, 0.f, 0.f};
            __builtin_amdgcn_s_setprio(1);
            #pragma unroll
            for (int kk = 0; kk < 6; ++kk) {
                short8 bq = *(const short8*)(lds + bqa[kk]);
                acc = __builtin_amdgcn_mfma_f32_16x16x32_bf16(
                        __builtin_bit_cast(short8, am[kk]), bq, acc, 0, 0, 0);
            }
            __builtin_amdgcn_s_setprio(0);

            // residual from live xt (inverse lrelu = min(h, 5h)); ch2 even -> u32
            unsigned int rv = *(const unsigned int*)(lds + ra);
            float h0 = bf2f(rv & 0xFFFFu), h1 = bf2f(rv >> 16);
            float xr0 = fminf(h0, 5.0f*h0);
            float xr1 = fminf(h1, 5.0f*h1);

            // same-lane GLU: regs (0,2) -> ch2, regs (1,3) -> ch2+1
            float g0 = glu_gate(acc[0] + bs0, acc[2] + bt0);
            float g1 = glu_gate(acc[1] + bs1, acc[3] + bt1);
            ob[(size_t)i*16]           = xr0 + g0;
            ob[16384 + (size_t)i*16]   = xr1 + g1;

            #pragma unroll
            for (int kk = 0; kk < 6; ++kk) bqa[kk] += 2048;
            ra += 2048;
        }
    }
}

extern "C" void kernel_launch(void* const* d_in, const int* in_sizes, int n_in,
                              void* d_out, int out_size, void* d_ws, size_t ws_size,
                              hipStream_t stream)
{
    const float* x      = (const float*)d_in[0];
    const float* kern   = (const float*)d_in[1];
    const float* bias   = (const float*)d_in[2];
    const float* conv_b = (const float*)d_in[4];
    float* out = (float*)d_out;

    if (ws_size < WS_NEED) return;   // harness provides >=100MB (verified R0)

    unsigned int* ktf = (unsigned int*)d_ws;
    unsigned int* wf  = (unsigned int*)((char*)d_ws + KTF_BYTES);

    wf_prep      <<<dim3(24),   dim3(TB), 0, stream>>>((const float*)d_in[3], wf);
    ktf_transpose<<<dim3(1536), dim3(TB), 0, stream>>>(kern, ktf);
    fused_kernel <<<dim3(2048), dim3(512), 0, stream>>>(x, bias, conv_b, ktf, wf, out);
    (void)in_sizes; (void)n_in; (void)out_size;
}